// Round 10
// baseline (77.822 us; speedup 1.0000x reference)
//
#include <hip/hip_runtime.h>
#include <hip/hip_fp8.h>

typedef float    f32x16 __attribute__((ext_vector_type(16)));
typedef _Float16 f16x8  __attribute__((ext_vector_type(8)));

#define NWAVES 4
#define TPW 4
#define TILES_PER_BLOCK (NWAVES * TPW)

// ---- fp8 e4m3 helpers (HW cvt on gfx950; encode/decode self-consistent) ----
__device__ __forceinline__ uint32_t enc4_fp8(float a, float b, float c, float d) {
#if __has_builtin(__builtin_amdgcn_cvt_pk_fp8_f32)
    int w = __builtin_amdgcn_cvt_pk_fp8_f32(a, b, 0, false);
    w     = __builtin_amdgcn_cvt_pk_fp8_f32(c, d, w, true);
    return (uint32_t)w;
#else
    __hip_fp8_e4m3 e0(a), e1(b), e2(c), e3(d);
    return (uint32_t)e0.__x | ((uint32_t)e1.__x << 8) |
           ((uint32_t)e2.__x << 16) | ((uint32_t)e3.__x << 24);
#endif
}

__device__ __forceinline__ void dec4_fp8(uint32_t w, _Float16* o) {
#if __has_builtin(__builtin_amdgcn_cvt_pk_f32_fp8)
    const auto f01 = __builtin_amdgcn_cvt_pk_f32_fp8((int)w, false); // bytes 0,1
    const auto f23 = __builtin_amdgcn_cvt_pk_f32_fp8((int)w, true);  // bytes 2,3
    const auto h01 = __builtin_amdgcn_cvt_pkrtz(f01[0], f01[1]);     // exact: e4m3 ⊂ f16
    const auto h23 = __builtin_amdgcn_cvt_pkrtz(f23[0], f23[1]);
    o[0] = h01[0]; o[1] = h01[1]; o[2] = h23[0]; o[3] = h23[1];
#else
    #pragma unroll
    for (int j = 0; j < 4; ++j) {
        __hip_fp8_e4m3 t; t.__x = (unsigned char)(w >> (8 * j));
        o[j] = (_Float16)(float)t;
    }
#endif
}

__device__ __forceinline__ f16x8 dec8_fp8(uint2 u) {
    _Float16 tmp[8];
    dec4_fp8(u.x, tmp);
    dec4_fp8(u.y, tmp + 4);
    f16x8 v;
    #pragma unroll
    for (int j = 0; j < 8; ++j) v[j] = tmp[j];
    return v;
}

// ---------------- prep: f32 node tables -> fp8 tables in d_ws ----------------
__global__ __launch_bounds__(256) void prep_fp8(
    const float* __restrict__ zi, const float* __restrict__ zj,
    uint2* __restrict__ zif8, uint2* __restrict__ zjf8, const int nChunkPer)
{
    const int stride = gridDim.x * blockDim.x;
    for (int c = blockIdx.x * blockDim.x + threadIdx.x; c < 2 * nChunkPer; c += stride) {
        const float* s;
        uint2* d;
        int cc;
        if (c < nChunkPer) { cc = c; s = zi + (size_t)cc * 8; d = zif8 + cc; }
        else { cc = c - nChunkPer; s = zj + (size_t)cc * 8; d = zjf8 + cc; }
        const float4 a0 = *reinterpret_cast<const float4*>(s);
        const float4 a1 = *reinterpret_cast<const float4*>(s + 4);
        uint2 w;
        w.x = enc4_fp8(a0.x, a0.y, a0.z, a0.w);
        w.y = enc4_fp8(a1.x, a1.y, a1.z, a1.w);
        *d = w;
    }
}

// ---------------- main ----------------
// Per edge: raw = concat(zi[src] (64), zj[dst] (64));
// hid = relu(raw @ W1^T + b1) [128]; score = sigmoid(hid . W3 + b3).
// neg_score == pos_score (source bug: both scored from raw_pos).
// Skeleton = r4 (60.5 us proven): no t-unroll, depth-1 idx prefetch only,
// no min-wave launch_bounds. FP8 path: raw px[8] (16 regs) + per-kk decode.
template<bool FP8>
__global__ __launch_bounds__(256) void graphlp_mfma(
    const float* __restrict__ zi, const float* __restrict__ zj,
    const unsigned char* __restrict__ zif8, const unsigned char* __restrict__ zjf8,
    const float* __restrict__ W1, const float* __restrict__ b1p,
    const float* __restrict__ W3, const float* __restrict__ b3p,
    const int* __restrict__ psrc, const int* __restrict__ pdst,
    float* __restrict__ out, const int nEdges, const int nTiles)
{
    // W1 as f16, swizzled: byte = row*256 + ((k*2) ^ ((row&7)<<4)); 32 KiB
    __shared__ uint4 w1s[2048];
    char* lds = reinterpret_cast<char*>(w1s);
    const int tid = threadIdx.x;

    #pragma unroll
    for (int i = 0; i < 8; ++i) {
        const int ch  = tid + i * 256;   // 2048 chunks of 8 f32
        const int row = ch >> 4;         // 0..127 (hidden unit n)
        const int kg  = ch & 15;         // 8-wide k group
        const float* s = W1 + row * 128 + kg * 8;
        const float4 a0 = *reinterpret_cast<const float4*>(s);
        const float4 a1 = *reinterpret_cast<const float4*>(s + 4);
        f16x8 v;
        v[0]=(_Float16)a0.x; v[1]=(_Float16)a0.y; v[2]=(_Float16)a0.z; v[3]=(_Float16)a0.w;
        v[4]=(_Float16)a1.x; v[5]=(_Float16)a1.y; v[6]=(_Float16)a1.z; v[7]=(_Float16)a1.w;
        const int off = row * 256 + ((kg * 16) ^ ((row & 7) << 4));
        *reinterpret_cast<f16x8*>(lds + off) = v;
    }
    __syncthreads();

    const int lane = tid & 63;
    const int wav  = tid >> 6;
    const int lr   = lane & 31;   // edge-row / n-col within 32
    const int lq   = lane >> 5;   // k-half selector

    float b1v[4], w3v[4];
    #pragma unroll
    for (int nb = 0; nb < 4; ++nb) {
        b1v[nb] = b1p[nb * 32 + lr];
        w3v[nb] = W3[nb * 32 + lr];
    }
    const float b3 = b3p[0];

    // consecutive tiles per block (r4 mapping; grid-stride regressed r2)
    int si = 0, di = 0;
    {
        const int g0 = blockIdx.x * TILES_PER_BLOCK + wav;  // t=0 tile
        if (g0 < nTiles) {
            const int e = min(g0 * 32 + lr, nEdges - 1);
            si = psrc[e]; di = pdst[e];
        }
    }

    for (int t = 0; t < TPW; ++t) {
        const int g = blockIdx.x * TILES_PER_BLOCK + t * NWAVES + wav;
        if (g >= nTiles) break;          // wave-uniform

        // prefetch next tile's indices (hide idx->gather dependency)
        int si_n = 0, di_n = 0;
        if (t + 1 < TPW) {
            const int gn = g + NWAVES;
            if (gn < nTiles) {
                const int en = min(gn * 32 + lr, nEdges - 1);
                si_n = psrc[en]; di_n = pdst[en];
            }
        }

        // A data: lane owns raw[lr][kk*16 + lq*8 .. +8)
        uint2 px[8];                 // fp8 path: 16 VGPRs of raw A data
        f16x8 afrag[8];              // f32 path only (32 VGPRs)
        if constexpr (FP8) {
            const unsigned char* __restrict__ sp = zif8 + (size_t)si * 64;
            const unsigned char* __restrict__ dp = zjf8 + (size_t)di * 64;
            #pragma unroll
            for (int kk = 0; kk < 4; ++kk) {
                px[kk]     = *reinterpret_cast<const uint2*>(sp + kk * 16 + lq * 8);
                px[kk + 4] = *reinterpret_cast<const uint2*>(dp + kk * 16 + lq * 8);
            }
        } else {
            const float* __restrict__ sp = zi + (size_t)si * 64;
            const float* __restrict__ dp = zj + (size_t)di * 64;
            #pragma unroll
            for (int kk = 0; kk < 8; ++kk) {
                const int kb = kk * 16 + lq * 8;             // 0..120, step 8
                const float* p = (kk < 4) ? (sp + kb) : (dp + kb - 64);
                const float4 a0 = *reinterpret_cast<const float4*>(p);
                const float4 a1 = *reinterpret_cast<const float4*>(p + 4);
                f16x8 v;
                v[0]=(_Float16)a0.x; v[1]=(_Float16)a0.y; v[2]=(_Float16)a0.z; v[3]=(_Float16)a0.w;
                v[4]=(_Float16)a1.x; v[5]=(_Float16)a1.y; v[6]=(_Float16)a1.z; v[7]=(_Float16)a1.w;
                afrag[kk] = v;
            }
        }

        float pr[16];
        #pragma unroll
        for (int r = 0; r < 16; ++r) pr[r] = 0.0f;

        // nb processed in pairs: 2x16 acc regs live instead of 4x16
        #pragma unroll
        for (int nbp = 0; nbp < 2; ++nbp) {
            if constexpr (FP8) {
                if (nbp) {
                    // CSE fence: force pass-2 to re-decode px instead of
                    // keeping 8 decoded f16x8 live across passes (reg tier!)
                    #pragma unroll
                    for (int kk = 0; kk < 8; ++kk)
                        asm volatile("" : "+v"(px[kk].x), "+v"(px[kk].y));
                }
            }
            const float bb0 = b1v[2*nbp], bb1 = b1v[2*nbp + 1];
            f32x16 acc0, acc1;
            #pragma unroll
            for (int r = 0; r < 16; ++r) { acc0[r] = bb0; acc1[r] = bb1; }  // bias via C-in
            const int n0 = (2*nbp)     * 32 + lr;            // W1 rows
            const int n1 = (2*nbp + 1) * 32 + lr;
            __builtin_amdgcn_s_setprio(1);
            #pragma unroll
            for (int kk = 0; kk < 8; ++kk) {
                f16x8 a;
                if constexpr (FP8) a = dec8_fp8(px[kk]);     // 4 regs, short-lived
                else               a = afrag[kk];
                const int kx = kk * 32 + lq * 16;
                const f16x8 bf0 = *reinterpret_cast<const f16x8*>(
                    lds + n0 * 256 + (kx ^ ((n0 & 7) << 4)));
                const f16x8 bf1 = *reinterpret_cast<const f16x8*>(
                    lds + n1 * 256 + (kx ^ ((n1 & 7) << 4)));
                acc0 = __builtin_amdgcn_mfma_f32_32x32x16_f16(a, bf0, acc0, 0, 0, 0);
                acc1 = __builtin_amdgcn_mfma_f32_32x32x16_f16(a, bf1, acc1, 0, 0, 0);
            }
            __builtin_amdgcn_s_setprio(0);
            const float ww0 = w3v[2*nbp], ww1 = w3v[2*nbp + 1];
            #pragma unroll
            for (int r = 0; r < 16; ++r) {
                pr[r] = fmaf(fmaxf(acc0[r], 0.0f), ww0, pr[r]);
                pr[r] = fmaf(fmaxf(acc1[r], 0.0f), ww1, pr[r]);
            }
        }

        // fold-reduce over the 32 n-lanes: halve reg count each stage
        float p8[8];
        #pragma unroll
        for (int r = 0; r < 8; ++r) {
            const float lo = pr[r], hi = pr[r + 8];
            const float sent = (lane & 1) ? lo : hi;
            const float got  = __shfl_xor(sent, 1);
            p8[r] = ((lane & 1) ? hi : lo) + got;
        }
        float p4[4];
        #pragma unroll
        for (int r = 0; r < 4; ++r) {
            const float lo = p8[r], hi = p8[r + 4];
            const float sent = (lane & 2) ? lo : hi;
            const float got  = __shfl_xor(sent, 2);
            p4[r] = ((lane & 2) ? hi : lo) + got;
        }
        float p2[2];
        #pragma unroll
        for (int r = 0; r < 2; ++r) {
            const float lo = p4[r], hi = p4[r + 2];
            const float sent = (lane & 4) ? lo : hi;
            const float got  = __shfl_xor(sent, 4);
            p2[r] = ((lane & 4) ? hi : lo) + got;
        }
        float p1;
        {
            const float lo = p2[0], hi = p2[1];
            const float sent = (lane & 8) ? lo : hi;
            const float got  = __shfl_xor(sent, 8);
            p1 = ((lane & 8) ? hi : lo) + got;
        }
        p1 += __shfl_xor(p1, 16);

        // lane -> original reg index rid; edge m = (rid&3) + 8*(rid>>2) + 4*lq
        const int rid = 8 * (lane & 1) + 4 * ((lane >> 1) & 1)
                      + 2 * ((lane >> 2) & 1) + ((lane >> 3) & 1);
        const int m  = (rid & 3) + 8 * (rid >> 2) + 4 * lq;
        const int eo = g * 32 + m;
        if (eo < nEdges) {
            const float sc = 1.0f / (1.0f + __expf(-(p1 + b3)));
            if (lane & 16) out[nEdges + eo] = sc;   // neg_score (== pos)
            else           out[eo] = sc;            // pos_score
        }

        si = si_n; di = di_n;
    }
}

extern "C" void kernel_launch(void* const* d_in, const int* in_sizes, int n_in,
                              void* d_out, int out_size, void* d_ws, size_t ws_size,
                              hipStream_t stream)
{
    const float* zi = (const float*)d_in[0];
    const float* zj = (const float*)d_in[1];
    // d_in[2] = zn  (unused: neg path is dead code in the reference)
    const float* W1 = (const float*)d_in[3];
    const float* b1 = (const float*)d_in[4];
    const float* W3 = (const float*)d_in[5];
    const float* b3 = (const float*)d_in[6];
    const int* psrc = (const int*)d_in[7];
    const int* pdst = (const int*)d_in[8];
    float* out = (float*)d_out;

    const int nEdges = in_sizes[7];
    const int nNodesI = in_sizes[0] / 64;   // zi rows
    const int nNodesJ = in_sizes[1] / 64;   // zj rows
    const int nTiles = (nEdges + 31) / 32;
    const int nBlocks = (nTiles + TILES_PER_BLOCK - 1) / TILES_PER_BLOCK;

    const size_t bytesI = (size_t)nNodesI * 64;   // 1 byte per element
    const size_t bytesJ = (size_t)nNodesJ * 64;
    const bool useF8 = (ws_size >= bytesI + bytesJ);

    if (useF8) {
        unsigned char* zif8 = (unsigned char*)d_ws;
        unsigned char* zjf8 = (unsigned char*)d_ws + bytesI;
        const int nChunkPer = nNodesI * 64 / 8;
        hipLaunchKernelGGL(prep_fp8, dim3(2048), dim3(256), 0, stream,
                           zi, zj, (uint2*)zif8, (uint2*)zjf8, nChunkPer);
        hipLaunchKernelGGL((graphlp_mfma<true>), dim3(nBlocks), dim3(256), 0, stream,
                           zi, zj, zif8, zjf8, W1, b1, W3, b3, psrc, pdst,
                           out, nEdges, nTiles);
    } else {
        hipLaunchKernelGGL((graphlp_mfma<false>), dim3(nBlocks), dim3(256), 0, stream,
                           zi, zj, (const unsigned char*)nullptr, (const unsigned char*)nullptr,
                           W1, b1, W3, b3, psrc, pdst, out, nEdges, nTiles);
    }
}

// Round 11
// 71.667 us; speedup vs baseline: 1.0859x; 1.0859x over previous
//
#include <hip/hip_runtime.h>
#include <hip/hip_fp8.h>

typedef float    f32x16 __attribute__((ext_vector_type(16)));
typedef _Float16 f16x8  __attribute__((ext_vector_type(8)));
typedef long     i64;

#define NWAVES 4
#define TPW 4
#define TILES_PER_BLOCK (NWAVES * TPW)

// ---- fp8 e4m3 helpers (HW cvt on gfx950) ----
__device__ __forceinline__ uint32_t enc4_fp8(float a, float b, float c, float d) {
#if __has_builtin(__builtin_amdgcn_cvt_pk_fp8_f32)
    int w = __builtin_amdgcn_cvt_pk_fp8_f32(a, b, 0, false);
    w     = __builtin_amdgcn_cvt_pk_fp8_f32(c, d, w, true);
    return (uint32_t)w;
#else
    __hip_fp8_e4m3 e0(a), e1(b), e2(c), e3(d);
    return (uint32_t)e0.__x | ((uint32_t)e1.__x << 8) |
           ((uint32_t)e2.__x << 16) | ((uint32_t)e3.__x << 24);
#endif
}

__device__ __forceinline__ void dec4_fp8f(uint32_t w, float* o) {
#if __has_builtin(__builtin_amdgcn_cvt_pk_f32_fp8)
    const auto f01 = __builtin_amdgcn_cvt_pk_f32_fp8((int)w, false);
    const auto f23 = __builtin_amdgcn_cvt_pk_f32_fp8((int)w, true);
    o[0] = f01[0]; o[1] = f01[1]; o[2] = f23[0]; o[3] = f23[1];
#else
    #pragma unroll
    for (int j = 0; j < 4; ++j) {
        __hip_fp8_e4m3 t; t.__x = (unsigned char)(w >> (8 * j));
        o[j] = (float)t;
    }
#endif
}

__device__ __forceinline__ i64 mk64(uint32_t lo, uint32_t hi) {
    return (i64)(((unsigned long long)hi << 32) | (unsigned long long)lo);
}

// ---------------- prep A: f32 node tables -> fp8 tables in d_ws ----------------
__global__ __launch_bounds__(256) void prep_fp8(
    const float* __restrict__ zi, const float* __restrict__ zj,
    uint2* __restrict__ zif8, uint2* __restrict__ zjf8, const int nChunkPer)
{
    const int stride = gridDim.x * blockDim.x;
    for (int c = blockIdx.x * blockDim.x + threadIdx.x; c < 2 * nChunkPer; c += stride) {
        const float* s;
        uint2* d;
        int cc;
        if (c < nChunkPer) { cc = c; s = zi + (size_t)cc * 8; d = zif8 + cc; }
        else { cc = c - nChunkPer; s = zj + (size_t)cc * 8; d = zjf8 + cc; }
        const float4 a0 = *reinterpret_cast<const float4*>(s);
        const float4 a1 = *reinterpret_cast<const float4*>(s + 4);
        uint2 w;
        w.x = enc4_fp8(a0.x, a0.y, a0.z, a0.w);
        w.y = enc4_fp8(a1.x, a1.y, a1.z, a1.w);
        *d = w;
    }
}

// ---------------- prep B: W1 -> fp8 hi + fp8 residual*16, k-permuted pack ----
// chunk c (0..2047): n = c>>4, q = c&15, kk = q>>1, lq = q&1.
// source k-base: kk<4 -> lq*32+kk*8 (zi half), else 64+lq*32+(kk-4)*8 (zj half).
// pack[c] = uint4{ hi01, hi23, res01, res23 } (16 B).
__global__ __launch_bounds__(256) void prep_w1(
    const float* __restrict__ W1, uint4* __restrict__ w1pack)
{
    const int c = blockIdx.x * blockDim.x + threadIdx.x;
    if (c >= 2048) return;
    const int n  = c >> 4, q = c & 15;
    const int kk = q >> 1, lq = q & 1;
    const int kbase = (kk < 4) ? (lq * 32 + kk * 8) : (64 + lq * 32 + (kk - 4) * 8);
    const float* w = W1 + n * 128 + kbase;
    const float4 w0 = *reinterpret_cast<const float4*>(w);
    const float4 w1 = *reinterpret_cast<const float4*>(w + 4);
    const uint32_t h0 = enc4_fp8(w0.x, w0.y, w0.z, w0.w);
    const uint32_t h1 = enc4_fp8(w1.x, w1.y, w1.z, w1.w);
    float d0[4], d1[4];
    dec4_fp8f(h0, d0);
    dec4_fp8f(h1, d1);
    const uint32_t r0 = enc4_fp8((w0.x - d0[0]) * 16.0f, (w0.y - d0[1]) * 16.0f,
                                 (w0.z - d0[2]) * 16.0f, (w0.w - d0[3]) * 16.0f);
    const uint32_t r1 = enc4_fp8((w1.x - d1[0]) * 16.0f, (w1.y - d1[1]) * 16.0f,
                                 (w1.z - d1[2]) * 16.0f, (w1.w - d1[3]) * 16.0f);
    uint4 o; o.x = h0; o.y = h1; o.z = r0; o.w = r1;
    w1pack[c] = o;
}

// ---------------- main ----------------
// Per edge: raw = concat(zi[src] (64), zj[dst] (64));
// hid = relu(raw @ W1^T + b1) [128]; score = sigmoid(hid . W3 + b3).
// neg_score == pos_score (source bug: both scored from raw_pos).
// r4 skeleton; A path = raw fp8 -> native fp8 MFMA (zero decode),
// W1 = fp8 hi + fp8 res/16 (two MFMAs per b128 read).
template<bool FP8>
__global__ __launch_bounds__(256) void graphlp_mfma(
    const float* __restrict__ zi, const float* __restrict__ zj,
    const unsigned char* __restrict__ zif8, const unsigned char* __restrict__ zjf8,
    const uint4* __restrict__ w1pack,
    const float* __restrict__ W1, const float* __restrict__ b1p,
    const float* __restrict__ W3, const float* __restrict__ b3p,
    const int* __restrict__ psrc, const int* __restrict__ pdst,
    float* __restrict__ out, const int nEdges, const int nTiles)
{
    // 32 KiB LDS; FP8: packed hi/res chunks at n*256 + ((q*16) ^ ((n&7)<<4))
    __shared__ uint4 w1s[2048];
    char* lds = reinterpret_cast<char*>(w1s);
    const int tid = threadIdx.x;

    if constexpr (FP8) {
        #pragma unroll
        for (int i = 0; i < 8; ++i) {
            const int ch = tid + i * 256;   // 0..2047
            const int n  = ch >> 4;
            const int q  = ch & 15;
            const uint4 v = w1pack[ch];
            const int off = n * 256 + ((q * 16) ^ ((n & 7) << 4));
            *reinterpret_cast<uint4*>(lds + off) = v;
        }
    } else {
        #pragma unroll
        for (int i = 0; i < 8; ++i) {
            const int ch  = tid + i * 256;   // 2048 chunks of 8 f32
            const int row = ch >> 4;
            const int kg  = ch & 15;
            const float* s = W1 + row * 128 + kg * 8;
            const float4 a0 = *reinterpret_cast<const float4*>(s);
            const float4 a1 = *reinterpret_cast<const float4*>(s + 4);
            f16x8 v;
            v[0]=(_Float16)a0.x; v[1]=(_Float16)a0.y; v[2]=(_Float16)a0.z; v[3]=(_Float16)a0.w;
            v[4]=(_Float16)a1.x; v[5]=(_Float16)a1.y; v[6]=(_Float16)a1.z; v[7]=(_Float16)a1.w;
            const int off = row * 256 + ((kg * 16) ^ ((row & 7) << 4));
            *reinterpret_cast<f16x8*>(lds + off) = v;
        }
    }
    __syncthreads();

    const int lane = tid & 63;
    const int wav  = tid >> 6;
    const int lr   = lane & 31;   // edge-row / n-col within 32
    const int lq   = lane >> 5;   // k-half selector

    float b1v[4], w3v[4];
    #pragma unroll
    for (int nb = 0; nb < 4; ++nb) {
        b1v[nb] = b1p[nb * 32 + lr];
        w3v[nb] = W3[nb * 32 + lr];
    }
    const float b3 = b3p[0];

    // consecutive tiles per block (r4 mapping; grid-stride regressed r2)
    int si = 0, di = 0;
    {
        const int g0 = blockIdx.x * TILES_PER_BLOCK + wav;
        if (g0 < nTiles) {
            const int e = min(g0 * 32 + lr, nEdges - 1);
            si = psrc[e]; di = pdst[e];
        }
    }

    for (int t = 0; t < TPW; ++t) {
        const int g = blockIdx.x * TILES_PER_BLOCK + t * NWAVES + wav;
        if (g >= nTiles) break;          // wave-uniform

        // prefetch next tile's indices (hide idx->gather dependency)
        int si_n = 0, di_n = 0;
        if (t + 1 < TPW) {
            const int gn = g + NWAVES;
            if (gn < nTiles) {
                const int en = min(gn * 32 + lr, nEdges - 1);
                si_n = psrc[en]; di_n = pdst[en];
            }
        }

        float pr[16];
        #pragma unroll
        for (int r = 0; r < 16; ++r) pr[r] = 0.0f;

        if constexpr (FP8) {
            // A: lane (lr,lq) reads contiguous 32 B of each 64 B row -> the
            // uint4 components ARE the 8 fp8 MFMA A-operands (k-permuted).
            const unsigned char* __restrict__ sp = zif8 + (size_t)si * 64;
            const unsigned char* __restrict__ dp = zjf8 + (size_t)di * 64;
            const uint4 as0 = *reinterpret_cast<const uint4*>(sp + lq * 32);
            const uint4 as1 = *reinterpret_cast<const uint4*>(sp + lq * 32 + 16);
            const uint4 ad0 = *reinterpret_cast<const uint4*>(dp + lq * 32);
            const uint4 ad1 = *reinterpret_cast<const uint4*>(dp + lq * 32 + 16);
            i64 aop[8];
            aop[0] = mk64(as0.x, as0.y); aop[1] = mk64(as0.z, as0.w);
            aop[2] = mk64(as1.x, as1.y); aop[3] = mk64(as1.z, as1.w);
            aop[4] = mk64(ad0.x, ad0.y); aop[5] = mk64(ad0.z, ad0.w);
            aop[6] = mk64(ad1.x, ad1.y); aop[7] = mk64(ad1.z, ad1.w);

            #pragma unroll
            for (int nb = 0; nb < 4; ++nb) {
                const float bb = b1v[nb];
                f32x16 acc, accr;
                #pragma unroll
                for (int r = 0; r < 16; ++r) { acc[r] = bb; accr[r] = 0.0f; }
                const int n   = nb * 32 + lr;
                const int nsw = (n & 7) << 4;
                const int nbase = n * 256;
                __builtin_amdgcn_s_setprio(1);
                #pragma unroll
                for (int kk = 0; kk < 8; ++kk) {
                    const int off = nbase + (((kk * 2 + lq) * 16) ^ nsw);
                    const uint4 w = *reinterpret_cast<const uint4*>(lds + off);
                    acc  = __builtin_amdgcn_mfma_f32_32x32x16_fp8_fp8(
                               aop[kk], mk64(w.x, w.y), acc,  0, 0, 0);
                    accr = __builtin_amdgcn_mfma_f32_32x32x16_fp8_fp8(
                               aop[kk], mk64(w.z, w.w), accr, 0, 0, 0);
                }
                __builtin_amdgcn_s_setprio(0);
                const float ww = w3v[nb];
                #pragma unroll
                for (int r = 0; r < 16; ++r) {
                    const float h = fmaf(accr[r], 0.0625f, acc[r]);
                    pr[r] = fmaf(fmaxf(h, 0.0f), ww, pr[r]);
                }
            }
        } else {
            // f32 fallback: r4-proven f16 path
            f16x8 afrag[8];
            const float* __restrict__ sp = zi + (size_t)si * 64;
            const float* __restrict__ dp = zj + (size_t)di * 64;
            #pragma unroll
            for (int kk = 0; kk < 8; ++kk) {
                const int kb = kk * 16 + lq * 8;
                const float* p = (kk < 4) ? (sp + kb) : (dp + kb - 64);
                const float4 a0 = *reinterpret_cast<const float4*>(p);
                const float4 a1 = *reinterpret_cast<const float4*>(p + 4);
                f16x8 v;
                v[0]=(_Float16)a0.x; v[1]=(_Float16)a0.y; v[2]=(_Float16)a0.z; v[3]=(_Float16)a0.w;
                v[4]=(_Float16)a1.x; v[5]=(_Float16)a1.y; v[6]=(_Float16)a1.z; v[7]=(_Float16)a1.w;
                afrag[kk] = v;
            }
            #pragma unroll
            for (int nbp = 0; nbp < 2; ++nbp) {
                const float bb0 = b1v[2*nbp], bb1 = b1v[2*nbp + 1];
                f32x16 acc0, acc1;
                #pragma unroll
                for (int r = 0; r < 16; ++r) { acc0[r] = bb0; acc1[r] = bb1; }
                const int n0 = (2*nbp)     * 32 + lr;
                const int n1 = (2*nbp + 1) * 32 + lr;
                #pragma unroll
                for (int kk = 0; kk < 8; ++kk) {
                    const int kx = kk * 32 + lq * 16;
                    const f16x8 bf0 = *reinterpret_cast<const f16x8*>(
                        lds + n0 * 256 + (kx ^ ((n0 & 7) << 4)));
                    const f16x8 bf1 = *reinterpret_cast<const f16x8*>(
                        lds + n1 * 256 + (kx ^ ((n1 & 7) << 4)));
                    acc0 = __builtin_amdgcn_mfma_f32_32x32x16_f16(afrag[kk], bf0, acc0, 0, 0, 0);
                    acc1 = __builtin_amdgcn_mfma_f32_32x32x16_f16(afrag[kk], bf1, acc1, 0, 0, 0);
                }
                const float ww0 = w3v[2*nbp], ww1 = w3v[2*nbp + 1];
                #pragma unroll
                for (int r = 0; r < 16; ++r) {
                    pr[r] = fmaf(fmaxf(acc0[r], 0.0f), ww0, pr[r]);
                    pr[r] = fmaf(fmaxf(acc1[r], 0.0f), ww1, pr[r]);
                }
            }
        }

        // fold-reduce over the 32 n-lanes: halve reg count each stage
        float p8[8];
        #pragma unroll
        for (int r = 0; r < 8; ++r) {
            const float lo = pr[r], hi = pr[r + 8];
            const float sent = (lane & 1) ? lo : hi;
            const float got  = __shfl_xor(sent, 1);
            p8[r] = ((lane & 1) ? hi : lo) + got;
        }
        float p4[4];
        #pragma unroll
        for (int r = 0; r < 4; ++r) {
            const float lo = p8[r], hi = p8[r + 4];
            const float sent = (lane & 2) ? lo : hi;
            const float got  = __shfl_xor(sent, 2);
            p4[r] = ((lane & 2) ? hi : lo) + got;
        }
        float p2[2];
        #pragma unroll
        for (int r = 0; r < 2; ++r) {
            const float lo = p4[r], hi = p4[r + 2];
            const float sent = (lane & 4) ? lo : hi;
            const float got  = __shfl_xor(sent, 4);
            p2[r] = ((lane & 4) ? hi : lo) + got;
        }
        float p1;
        {
            const float lo = p2[0], hi = p2[1];
            const float sent = (lane & 8) ? lo : hi;
            const float got  = __shfl_xor(sent, 8);
            p1 = ((lane & 8) ? hi : lo) + got;
        }
        p1 += __shfl_xor(p1, 16);

        // lane -> original reg index rid; edge m = (rid&3) + 8*(rid>>2) + 4*lq
        const int rid = 8 * (lane & 1) + 4 * ((lane >> 1) & 1)
                      + 2 * ((lane >> 2) & 1) + ((lane >> 3) & 1);
        const int m  = (rid & 3) + 8 * (rid >> 2) + 4 * lq;
        const int eo = g * 32 + m;
        if (eo < nEdges) {
            const float sc = 1.0f / (1.0f + __expf(-(p1 + b3)));
            if (lane & 16) out[nEdges + eo] = sc;   // neg_score (== pos)
            else           out[eo] = sc;            // pos_score
        }

        si = si_n; di = di_n;
    }
}

extern "C" void kernel_launch(void* const* d_in, const int* in_sizes, int n_in,
                              void* d_out, int out_size, void* d_ws, size_t ws_size,
                              hipStream_t stream)
{
    const float* zi = (const float*)d_in[0];
    const float* zj = (const float*)d_in[1];
    // d_in[2] = zn  (unused: neg path is dead code in the reference)
    const float* W1 = (const float*)d_in[3];
    const float* b1 = (const float*)d_in[4];
    const float* W3 = (const float*)d_in[5];
    const float* b3 = (const float*)d_in[6];
    const int* psrc = (const int*)d_in[7];
    const int* pdst = (const int*)d_in[8];
    float* out = (float*)d_out;

    const int nEdges = in_sizes[7];
    const int nNodesI = in_sizes[0] / 64;   // zi rows
    const int nNodesJ = in_sizes[1] / 64;   // zj rows
    const int nTiles = (nEdges + 31) / 32;
    const int nBlocks = (nTiles + TILES_PER_BLOCK - 1) / TILES_PER_BLOCK;

    const size_t bytesI = (size_t)nNodesI * 64;   // 1 byte per element
    const size_t bytesJ = (size_t)nNodesJ * 64;
    const size_t bytesW = 2048 * 16;              // W1 hi/res pack (32 KiB)
    const bool useF8 = (ws_size >= bytesI + bytesJ + bytesW);

    if (useF8) {
        unsigned char* zif8 = (unsigned char*)d_ws;
        unsigned char* zjf8 = (unsigned char*)d_ws + bytesI;
        uint4* w1pack = (uint4*)((unsigned char*)d_ws + bytesI + bytesJ);
        const int nChunkPer = nNodesI * 64 / 8;
        hipLaunchKernelGGL(prep_fp8, dim3(2048), dim3(256), 0, stream,
                           zi, zj, (uint2*)zif8, (uint2*)zjf8, nChunkPer);
        hipLaunchKernelGGL(prep_w1, dim3(8), dim3(256), 0, stream, W1, w1pack);
        hipLaunchKernelGGL((graphlp_mfma<true>), dim3(nBlocks), dim3(256), 0, stream,
                           zi, zj, zif8, zjf8, w1pack, W1, b1, W3, b3, psrc, pdst,
                           out, nEdges, nTiles);
    } else {
        hipLaunchKernelGGL((graphlp_mfma<false>), dim3(nBlocks), dim3(256), 0, stream,
                           zi, zj, (const unsigned char*)nullptr, (const unsigned char*)nullptr,
                           (const uint4*)nullptr, W1, b1, W3, b3, psrc, pdst,
                           out, nEdges, nTiles);
    }
}